// Round 8
// baseline (81.068 us; speedup 1.0000x reference)
//
#include <hip/hip_runtime.h>
#include <hip/hip_bf16.h>
#include <cstdint>

#define TOUT 505
#define TT   2048
#define QROWS 4040                // 8*505
#define KD   512
#define BK   128
#define NSTEP 4                   // KD/BK

typedef float f32x4 __attribute__((ext_vector_type(4)));
typedef __bf16 bf16x8 __attribute__((ext_vector_type(8)));

static __device__ __forceinline__ ushort f2bf(float f) {
  uint32_t u = __float_as_uint(f);
  uint32_t r = (u + 0x7fffu + ((u >> 16) & 1u)) >> 16;
  return (ushort)r;
}
static __device__ __forceinline__ float bf2f(ushort h) {
  return __uint_as_float(((uint32_t)h) << 16);
}

// ---- prep: Wq^T, Wv^T (LDS-tiled transpose) + Wk row-cast.  No x pass! ----
__global__ void prep_kernel(const float* __restrict__ Wq, const float* __restrict__ Wk,
                            const float* __restrict__ Wv,
                            ushort* __restrict__ wqt, ushort* __restrict__ wvt,
                            ushort* __restrict__ wkb) {
  const int bid = blockIdx.x;
  const int tid = threadIdx.x;
  if (bid < 128) {                        // transpose: 0-63 Wq, 64-127 Wv
    __shared__ ushort lds[64][66];        // 132B stride: conflict-free
    int mat = bid >> 6;
    int w = bid & 63;
    int k0 = (w >> 3) * 64, n0 = (w & 7) * 64;
    const float* W = mat ? Wv : Wq;
    ushort* dst = mat ? wvt : wqt;
    int nn = tid & 63;
    #pragma unroll
    for (int r = 0; r < 16; ++r) {
      int kk = r * 4 + (tid >> 6);
      lds[kk][nn] = f2bf(W[(size_t)(k0 + kk) * 512 + n0 + nn]);   // coalesced
    }
    __syncthreads();
    int kk2 = tid & 63;
    #pragma unroll
    for (int r = 0; r < 16; ++r) {
      int nn2 = r * 4 + (tid >> 6);
      dst[(size_t)(n0 + nn2) * 512 + k0 + kk2] = lds[kk2][nn2];   // coalesced
    }
  } else {                                // Wk row-major bf16 cast (no transpose)
    int idx = (bid - 128) * 256 + tid;    // 0..32767, 8 elems each
    int e0 = idx * 8;
    float4 a = *reinterpret_cast<const float4*>(Wk + e0);
    float4 b = *reinterpret_cast<const float4*>(Wk + e0 + 4);
    ushort v8[8] = {f2bf(a.x), f2bf(a.y), f2bf(a.z), f2bf(a.w),
                    f2bf(b.x), f2bf(b.y), f2bf(b.z), f2bf(b.w)};
    *reinterpret_cast<uint4*>(wkb + e0) = *reinterpret_cast<const uint4*>(v8);
  }
}

// ---- small GEMM (M=4096 logical 4040, N=512, K=512), 128^2 tile, BK=128 ----
// MODE 0: A = gathered x centers (fp32, reg-staged->bf16), bias=bq, out bf16 (qbuf)
// MODE 1: A = qbuf bf16 (linear, clamped),  no bias,        out bf16 (zbuf)
// MODE 2: A = ubuf bf16 (linear, clamped),  bias=bv,        out fp32 (d_out)
template <int MODE>
__global__ __launch_bounds__(256, 2) void gemm_kernel(
    const float* __restrict__ xf, const ushort* __restrict__ abuf,
    const ushort* __restrict__ bmat, const float* __restrict__ bias,
    ushort* __restrict__ obf, float* __restrict__ of32) {
  __shared__ ushort As[128 * 128];        // 32 KB
  __shared__ ushort Bs[128 * 128];        // 32 KB

  const int tid = threadIdx.x;
  const int lane = tid & 63;
  const int wv = tid >> 6;
  // XCD swizzle (128 blocks): XCD x gets contiguous swz chunk -> M-locality
  const int swz = (blockIdx.x & 7) * 16 + (blockIdx.x >> 3);
  const int m0 = (swz >> 2) * 128;
  const int n0 = (swz & 3) * 128;

  // staging geometry: 8 chunks/thread, chunk i -> dest row i*16+(tid>>4),
  // dest byte-col (tid&15)*16 within 256B row.
  const int srow = tid >> 4;
  const int colb = (tid & 15) * 16;
  const int scol = ((((colb & 127) ^ ((srow & 7) << 4)) + (colb & 128)) >> 1);

  const ushort* bSrc[8];
  const ushort* aSrc[8];       // MODE 1/2
  const float*  aSrcF[8];      // MODE 0
  uint          aDst[8];       // MODE 0 swizzled LDS byte
  #pragma unroll
  for (int i = 0; i < 8; ++i) {
    int row = i * 16 + srow;
    bSrc[i] = bmat + (size_t)(n0 + row) * 512 + scol;
    if (MODE == 0) {
      int r = m0 + row; if (r > QROWS - 1) r = QROWS - 1;
      int bb = r / TOUT;
      int tt = r - bb * TOUT;
      size_t arow = (size_t)bb * TT + (size_t)tt * 4 + 16;   // center row
      aSrcF[i] = xf + arow * 512 + (colb >> 1);
      aDst[i] = (uint)(row * 256 + (colb & 128) + ((colb & 127) ^ ((row & 7) << 4)));
    } else {
      int r = m0 + row; if (r > QROWS - 1) r = QROWS - 1;
      aSrc[i] = abuf + (size_t)r * 512 + scol;
    }
  }

  const int fr = lane & 15;
  const int fq = lane >> 4;
  const int wr = wv >> 1;
  const int wc = wv & 1;

  f32x4 acc[4][4];
  #pragma unroll
  for (int i = 0; i < 4; ++i)
    #pragma unroll
    for (int j = 0; j < 4; ++j) acc[i][j] = (f32x4){0.f, 0.f, 0.f, 0.f};

  for (int t = 0; t < NSTEP; ++t) {
    __syncthreads();
    const int koff = t * BK;
    #pragma unroll
    for (int i = 0; i < 8; ++i) {
      int ldst = i * 4096 + tid * 16;
      __builtin_amdgcn_global_load_lds(
          (const __attribute__((address_space(1))) unsigned int*)(bSrc[i] + koff),
          (__attribute__((address_space(3))) unsigned int*)((char*)Bs + ldst),
          16, 0, 0);
      if (MODE == 0) {
        float4 lo = *reinterpret_cast<const float4*>(aSrcF[i] + koff);
        float4 hi = *reinterpret_cast<const float4*>(aSrcF[i] + koff + 4);
        ushort v8[8] = {f2bf(lo.x), f2bf(lo.y), f2bf(lo.z), f2bf(lo.w),
                        f2bf(hi.x), f2bf(hi.y), f2bf(hi.z), f2bf(hi.w)};
        *reinterpret_cast<uint4*>((char*)As + aDst[i]) =
            *reinterpret_cast<const uint4*>(v8);
      } else {
        __builtin_amdgcn_global_load_lds(
            (const __attribute__((address_space(1))) unsigned int*)(aSrc[i] + koff),
            (__attribute__((address_space(3))) unsigned int*)((char*)As + ldst),
            16, 0, 0);
      }
    }
    __syncthreads();

    #pragma unroll
    for (int ks = 0; ks < 4; ++ks) {
      const int cab = ks * 64 + fq * 16;                 // byte col in 256B row
      bf16x8 af[4], bg[4];
      #pragma unroll
      for (int i = 0; i < 4; ++i) {
        int ra = wr * 64 + i * 16 + fr;
        af[i] = *reinterpret_cast<const bf16x8*>(
            (const char*)As + ra * 256 + (cab & 128) + ((cab & 127) ^ ((ra & 7) << 4)));
        int rb = wc * 64 + i * 16 + fr;
        bg[i] = *reinterpret_cast<const bf16x8*>(
            (const char*)Bs + rb * 256 + (cab & 128) + ((cab & 127) ^ ((rb & 7) << 4)));
      }
      #pragma unroll
      for (int i = 0; i < 4; ++i)
        #pragma unroll
        for (int j = 0; j < 4; ++j)
          acc[i][j] = __builtin_amdgcn_mfma_f32_16x16x32_bf16(af[i], bg[j], acc[i][j], 0, 0, 0);
    }
  }

  // epilogue.  D: row=(lane>>4)*4+r, col=lane&15
  #pragma unroll
  for (int j = 0; j < 4; ++j) {
    int col = n0 + wc * 64 + j * 16 + fr;               // 0..511
    float bvl = (MODE == 1) ? 0.f : bias[col];
    #pragma unroll
    for (int i = 0; i < 4; ++i) {
      int rowb = m0 + wr * 64 + i * 16 + fq * 4;
      #pragma unroll
      for (int r = 0; r < 4; ++r) {
        if (rowb + r < QROWS) {
          float v = acc[i][j][r] + bvl;
          if (MODE == 2) of32[(size_t)(rowb + r) * 512 + col] = v;
          else           obf[(size_t)(rowb + r) * 512 + col] = f2bf(v);
        }
      }
    }
  }
}

// ---- attention: stage fp32 x-window once; scores = z.x_f ; u = sum w*x_f ----
__global__ __launch_bounds__(256) void attn_kernel(
    const float* __restrict__ xf,    // [8*2048][512] fp32
    const ushort* __restrict__ zbuf, // [4040][512] bf16
    ushort* __restrict__ ubuf) {     // [4040][512] bf16
  __shared__ float xw[32 * 512];     // 64 KB window
  __shared__ float zl[512];
  __shared__ float s_lds[32];
  __shared__ float p_lds[32];

  const int bid = blockIdx.x;
  const int b = bid & 7;             // batch pinned to XCD
  const int t = bid >> 3;
  const size_t base_row = (size_t)b * TT + (size_t)t * 4;
  const int r = b * TOUT + t;
  const int tid = threadIdx.x;
  const int lane = tid & 63;
  const int wv = tid >> 6;

  // stage 32 rows x 2KB, linear dest (no swizzle needed: cols vary per lane)
  #pragma unroll
  for (int i = 0; i < 16; ++i) {
    int dst = i * 4096 + tid * 16;
    int row = dst >> 11;
    int cf = (dst & 2047) >> 2;
    __builtin_amdgcn_global_load_lds(
        (const __attribute__((address_space(1))) unsigned int*)(xf + (base_row + row) * 512 + cf),
        (__attribute__((address_space(3))) unsigned int*)((char*)xw + dst),
        16, 0, 0);
  }
  {  // z row -> LDS fp32
    uint v = *reinterpret_cast<const uint*>(zbuf + (size_t)r * 512 + tid * 2);
    zl[tid * 2]     = bf2f((ushort)(v & 0xffffu));
    zl[tid * 2 + 1] = bf2f((ushort)(v >> 16));
  }
  __syncthreads();

  // scores: 8 lanes per filter tap f
  const int f = wv * 8 + (lane >> 3);
  const int sub = lane & 7;
  float acc = 0.f;
  #pragma unroll
  for (int j = 0; j < 8; ++j) {
    int d0 = (j * 8 + sub) * 8;
    const float* xr = xw + f * 512 + d0;
    float4 a = *reinterpret_cast<const float4*>(xr);
    float4 c = *reinterpret_cast<const float4*>(xr + 4);
    acc += zl[d0] * a.x + zl[d0 + 1] * a.y + zl[d0 + 2] * a.z + zl[d0 + 3] * a.w;
    acc += zl[d0 + 4] * c.x + zl[d0 + 5] * c.y + zl[d0 + 6] * c.z + zl[d0 + 7] * c.w;
  }
  acc += __shfl_xor(acc, 1);
  acc += __shfl_xor(acc, 2);
  acc += __shfl_xor(acc, 4);
  if (sub == 0) s_lds[f] = acc * 0.04419417382415922f;   // 1/sqrt(512)
  __syncthreads();

  float m = -1e30f;
  #pragma unroll
  for (int i = 0; i < 32; ++i) m = fmaxf(m, s_lds[i]);
  if (tid < 32) p_lds[tid] = __expf(s_lds[tid] - m);
  __syncthreads();
  float sum = 0.f;
  #pragma unroll
  for (int i = 0; i < 32; ++i) sum += p_lds[i];
  const float inv = 1.f / sum;

  // u = sum_f w_f * x_f  (2 dims/thread)
  const int d = tid * 2;
  float o0 = 0.f, o1 = 0.f;
  #pragma unroll
  for (int ff = 0; ff < 32; ++ff) {
    float w = p_lds[ff] * inv;
    o0 += w * xw[ff * 512 + d];
    o1 += w * xw[ff * 512 + d + 1];
  }
  uint pk = ((uint)f2bf(o1) << 16) | (uint)f2bf(o0);
  *reinterpret_cast<uint*>(ubuf + (size_t)r * 512 + d) = pk;
}

// ---------------- launch ----------------
extern "C" void kernel_launch(void* const* d_in, const int* in_sizes, int n_in,
                              void* d_out, int out_size, void* d_ws, size_t ws_size,
                              hipStream_t stream) {
  const float* x  = (const float*)d_in[0];
  const float* Wq = (const float*)d_in[1];
  const float* bq = (const float*)d_in[2];
  const float* Wk = (const float*)d_in[3];
  const float* Wv = (const float*)d_in[5];
  const float* bv = (const float*)d_in[6];
  float* out = (float*)d_out;

  char* ws = (char*)d_ws;
  ushort* wqt  = (ushort*)ws;                       // 0.5 MiB
  ushort* wvt  = (ushort*)(ws + 524288);            // 0.5 MiB
  ushort* wkb  = (ushort*)(ws + 1048576);           // 0.5 MiB
  ushort* qbuf = (ushort*)(ws + 1572864);           // 4 MiB  [4096][512] bf16
  ushort* zbuf = (ushort*)(ws + 1572864 + 4194304); // 4 MiB
  ushort* ubuf = (ushort*)(ws + 1572864 + 8388608); // 4 MiB

  hipLaunchKernelGGL(prep_kernel, dim3(256), dim3(256), 0, stream,
                     Wq, Wk, Wv, wqt, wvt, wkb);
  // q = gather(x) @ Wq^T + bq
  hipLaunchKernelGGL((gemm_kernel<0>), dim3(128), dim3(256), 0, stream,
                     x, (const ushort*)nullptr, wqt, bq, qbuf, (float*)nullptr);
  // z = q @ Wk^T   (scores in x-space; q.bk term is softmax-invariant)
  hipLaunchKernelGGL((gemm_kernel<1>), dim3(128), dim3(256), 0, stream,
                     (const float*)nullptr, qbuf, wkb, (const float*)nullptr, zbuf, (float*)nullptr);
  // attention in x-space: scores = z.x_f, u = sum w_f x_f
  hipLaunchKernelGGL(attn_kernel, dim3(QROWS), dim3(256), 0, stream, x, zbuf, ubuf);
  // out = u @ Wv^T + bv   (fp32 store)
  hipLaunchKernelGGL((gemm_kernel<2>), dim3(128), dim3(256), 0, stream,
                     (const float*)nullptr, ubuf, wvt, bv, (ushort*)nullptr, out);
}